// Round 2
// baseline (66322.534 us; speedup 1.0000x reference)
//
#include <hip/hip_runtime.h>
#include <math.h>

// Problem constants
#define D_    768
#define NH_   12
#define HD_   64
#define L_    12
#define P_    5
#define NL_   54      // 5 + 7*7
#define NS_   256     // 16*16
#define B_    128
#define ROWS_L (B_*NL_)   // 6912
#define ROWS_S (B_*NS_)   // 32768
#define SCALE_ 0.125f     // 1/sqrt(64)

// ---------------------------------------------------------------------------
// Generic tiled f32 GEMM: C(M,N) = A(M,K) @ B(K,N), all dims multiples of 64/16.
// EPI: 0 = store, 1 = C += acc (residual read from C), 2 = C += gate[c]*acc,
//      3 = store gelu(acc)
// ---------------------------------------------------------------------------
__device__ __forceinline__ float gelu_f(float x) {
  const float k0 = 0.7978845608028654f; // sqrt(2/pi)
  float x3 = x * x * x;
  float t = tanhf(k0 * (x + 0.044715f * x3));
  return 0.5f * x * (1.f + t);
}

template<int EPI>
__global__ void __launch_bounds__(256)
gemm_f32(const float* __restrict__ A, const float* __restrict__ Bw,
         float* __restrict__ C, const float* __restrict__ gate,
         int M, int N, int K)
{
  __shared__ float As[64][20];   // [row][k], pad 20
  __shared__ float Bs[16][68];   // [k][col], pad 68

  const int tid  = threadIdx.x;
  const int tx   = tid & 15;
  const int ty   = tid >> 4;
  const int brow = blockIdx.y << 6;
  const int bcol = blockIdx.x << 6;

  const int arow = tid & 63;
  const int akq  = (tid >> 6) << 2;   // 0,4,8,12
  const int bk   = tid >> 4;          // 0..15
  const int bc   = (tid & 15) << 2;   // 0..60

  const float* Aptr = A + (size_t)(brow + arow) * K + akq;
  const float* Bptr = Bw + (size_t)bk * N + bcol + bc;

  float acc[4][4] = {};

  for (int k0 = 0; k0 < K; k0 += 16) {
    float4 av = *(const float4*)(Aptr + k0);
    float4 bv = *(const float4*)(Bptr + (size_t)k0 * N);
    __syncthreads();
    *(float4*)&As[arow][akq] = av;
    *(float4*)&Bs[bk][bc]    = bv;
    __syncthreads();
    #pragma unroll
    for (int kk = 0; kk < 16; kk++) {
      float4 b4 = *(const float4*)&Bs[kk][tx << 2];
      float a0 = As[(ty << 2) + 0][kk];
      float a1 = As[(ty << 2) + 1][kk];
      float a2 = As[(ty << 2) + 2][kk];
      float a3 = As[(ty << 2) + 3][kk];
      acc[0][0] += a0*b4.x; acc[0][1] += a0*b4.y; acc[0][2] += a0*b4.z; acc[0][3] += a0*b4.w;
      acc[1][0] += a1*b4.x; acc[1][1] += a1*b4.y; acc[1][2] += a1*b4.z; acc[1][3] += a1*b4.w;
      acc[2][0] += a2*b4.x; acc[2][1] += a2*b4.y; acc[2][2] += a2*b4.z; acc[2][3] += a2*b4.w;
      acc[3][0] += a3*b4.x; acc[3][1] += a3*b4.y; acc[3][2] += a3*b4.z; acc[3][3] += a3*b4.w;
    }
  }

  #pragma unroll
  for (int i = 0; i < 4; i++) {
    float* cp = C + (size_t)(brow + (ty << 2) + i) * N + bcol + (tx << 2);
    float4 r;
    if (EPI == 0) {
      r.x = acc[i][0]; r.y = acc[i][1]; r.z = acc[i][2]; r.w = acc[i][3];
    } else if (EPI == 1) {
      float4 old = *(const float4*)cp;
      r.x = old.x + acc[i][0]; r.y = old.y + acc[i][1];
      r.z = old.z + acc[i][2]; r.w = old.w + acc[i][3];
    } else if (EPI == 2) {
      float4 old = *(const float4*)cp;
      float4 gv  = *(const float4*)(gate + bcol + (tx << 2));
      r.x = old.x + gv.x * acc[i][0]; r.y = old.y + gv.y * acc[i][1];
      r.z = old.z + gv.z * acc[i][2]; r.w = old.w + gv.w * acc[i][3];
    } else {
      r.x = gelu_f(acc[i][0]); r.y = gelu_f(acc[i][1]);
      r.z = gelu_f(acc[i][2]); r.w = gelu_f(acc[i][3]);
    }
    *(float4*)cp = r;
  }
}

// ---------------------------------------------------------------------------
// Fused attention per (b, h, q-chunk of 64): RoPE on load, online softmax.
// Q rows in registers; K/V staged in LDS 64-row tiles.
// rope tables: sin/cos laid out (n, 32); per-batch stride bstr (0 = shared).
// ---------------------------------------------------------------------------
__global__ void __launch_bounds__(64)
attn_fused(const float* __restrict__ Q, int ldq,
           const float* __restrict__ Kp, int ldk,
           const float* __restrict__ Vp, int ldv,
           float* __restrict__ O, int ldo,
           int Nq, int Nk,
           const float* __restrict__ qsin, const float* __restrict__ qcos,
           int qpre, int qbstr,
           const float* __restrict__ ksin, const float* __restrict__ kcos,
           int kpre, int kbstr)
{
  __shared__ float kS[64][64];
  __shared__ float vS[64][64];
  const int tid = threadIdx.x;
  const int b = blockIdx.z, h = blockIdx.y;
  const int qi = blockIdx.x * 64 + tid;
  const bool qact = qi < Nq;

  float qreg[64];
  if (qact) {
    const float4* qp = (const float4*)(Q + (size_t)(b * Nq + qi) * ldq + h * 64);
    #pragma unroll
    for (int d4 = 0; d4 < 16; d4++) {
      float4 t = qp[d4];
      qreg[d4*4+0] = t.x; qreg[d4*4+1] = t.y; qreg[d4*4+2] = t.z; qreg[d4*4+3] = t.w;
    }
    if (qi >= qpre) {
      const float* sp = qsin + (size_t)b * qbstr + (size_t)(qi - qpre) * 32;
      const float* cp = qcos + (size_t)b * qbstr + (size_t)(qi - qpre) * 32;
      #pragma unroll
      for (int d = 0; d < 32; d++) {
        float s = sp[d], c = cp[d];
        float x1 = qreg[d], x2 = qreg[d + 32];
        qreg[d]      = x1 * c - x2 * s;
        qreg[d + 32] = x2 * c + x1 * s;
      }
    }
  }

  float m = -1e30f, l = 0.f;
  float acc[64] = {};

  for (int kt = 0; kt < Nk; kt += 64) {
    const int rows = min(64, Nk - kt);
    __syncthreads();
    for (int r = 0; r < rows; r++) {
      const int n = kt + r;
      const size_t rowi = (size_t)(b * Nk + n);
      float kv = Kp[rowi * ldk + h * 64 + tid];
      float vv = Vp[rowi * ldv + h * 64 + tid];
      if (n >= kpre) {
        float pair = __shfl_xor(kv, 32);
        const int dd = tid & 31;
        const float* sp = ksin + (size_t)b * kbstr + (size_t)(n - kpre) * 32;
        const float* cp = kcos + (size_t)b * kbstr + (size_t)(n - kpre) * 32;
        float s = sp[dd], c = cp[dd];
        kv = (tid < 32) ? (kv * c - pair * s) : (kv * c + pair * s);
      }
      kS[r][tid] = kv;
      vS[r][tid] = vv;
    }
    __syncthreads();
    if (qact) {
      for (int kk = 0; kk < rows; kk++) {
        const float4* kr = (const float4*)kS[kk];
        float s = 0.f;
        #pragma unroll
        for (int d4 = 0; d4 < 16; d4++) {
          float4 kq = kr[d4];
          s += qreg[d4*4+0]*kq.x + qreg[d4*4+1]*kq.y + qreg[d4*4+2]*kq.z + qreg[d4*4+3]*kq.w;
        }
        s *= SCALE_;
        if (s > m) {
          float f = __expf(m - s);
          l *= f;
          #pragma unroll
          for (int d = 0; d < 64; d++) acc[d] *= f;
          m = s;
        }
        float p = __expf(s - m);
        l += p;
        const float4* vr = (const float4*)vS[kk];
        #pragma unroll
        for (int d4 = 0; d4 < 16; d4++) {
          float4 vq = vr[d4];
          acc[d4*4+0] += p*vq.x; acc[d4*4+1] += p*vq.y;
          acc[d4*4+2] += p*vq.z; acc[d4*4+3] += p*vq.w;
        }
      }
    }
  }

  if (qact) {
    float inv = 1.f / l;
    float4* op = (float4*)(O + (size_t)(b * Nq + qi) * ldo + h * 64);
    #pragma unroll
    for (int d4 = 0; d4 < 16; d4++) {
      float4 o;
      o.x = acc[d4*4+0]*inv; o.y = acc[d4*4+1]*inv;
      o.z = acc[d4*4+2]*inv; o.w = acc[d4*4+3]*inv;
      op[d4] = o;
    }
  }
}

// ---------------------------------------------------------------------------
// LayerNorm: one wave per row of 768, 4 rows per 256-thread block.
// ---------------------------------------------------------------------------
__global__ void __launch_bounds__(256)
ln_kernel(const float* __restrict__ X, float* __restrict__ Y,
          const float* __restrict__ g, const float* __restrict__ bb)
{
  const int row  = blockIdx.x * 4 + (threadIdx.x >> 6);
  const int lane = threadIdx.x & 63;
  const float* x = X + (size_t)row * 768;
  float4 v[3];
  float s = 0.f, ss = 0.f;
  #pragma unroll
  for (int i = 0; i < 3; i++) {
    v[i] = *(const float4*)(x + i * 256 + lane * 4);
    s  += v[i].x + v[i].y + v[i].z + v[i].w;
    ss += v[i].x*v[i].x + v[i].y*v[i].y + v[i].z*v[i].z + v[i].w*v[i].w;
  }
  #pragma unroll
  for (int o = 1; o < 64; o <<= 1) { s += __shfl_xor(s, o); ss += __shfl_xor(ss, o); }
  float mean = s * (1.f / 768.f);
  float var  = ss * (1.f / 768.f) - mean * mean;
  float inv  = rsqrtf(var + 1e-6f);
  float* y = Y + (size_t)row * 768;
  #pragma unroll
  for (int i = 0; i < 3; i++) {
    float4 gv = *(const float4*)(g  + i * 256 + lane * 4);
    float4 bv = *(const float4*)(bb + i * 256 + lane * 4);
    float4 o;
    o.x = (v[i].x - mean) * inv * gv.x + bv.x;
    o.y = (v[i].y - mean) * inv * gv.y + bv.y;
    o.z = (v[i].z - mean) * inv * gv.z + bv.z;
    o.w = (v[i].w - mean) * inv * gv.w + bv.w;
    *(float4*)(y + i * 256 + lane * 4) = o;
  }
}

// ---------------------------------------------------------------------------
// Init / rope-table kernels
// ---------------------------------------------------------------------------
__global__ void copy_f4(const float4* __restrict__ src, float4* __restrict__ dst, int n) {
  int i = blockIdx.x * blockDim.x + threadIdx.x;
  int stride = gridDim.x * blockDim.x;
  for (; i < n; i += stride) dst[i] = src[i];
}

__global__ void bcast_f4(const float4* __restrict__ src, float4* __restrict__ dst,
                         int per, int total) {
  int i = blockIdx.x * blockDim.x + threadIdx.x;
  int stride = gridDim.x * blockDim.x;
  for (; i < total; i += stride) dst[i] = src[i % per];
}

// local rope: (B,49,32) tables from centers/scales; t = iy*7+ix
__global__ void rope_local_k(const float* __restrict__ centers,
                             const float* __restrict__ scales,
                             float* __restrict__ lsin, float* __restrict__ lcos)
{
  int idx = blockIdx.x * blockDim.x + threadIdx.x;
  if (idx >= B_ * 49) return;
  int b = idx / 49, t = idx % 49;
  int iy = t / 7, ix = t % 7;
  float gy = (iy + 0.5f) / 7.f * 2.f - 1.f;
  float gx = (ix + 0.5f) / 7.f * 2.f - 1.f;
  float sc = scales[b];
  float py = centers[2 * b + 0] + sc * gy;
  float px = centers[2 * b + 1] + sc * gx;
  float* so = lsin + (size_t)idx * 32;
  float* co = lcos + (size_t)idx * 32;
  for (int j = 0; j < 16; j++) {
    float f  = powf(100.f, -(float)j / 16.f);
    float ay = py * f, ax = px * f;
    so[j]      = sinf(ay); co[j]      = cosf(ay);
    so[j + 16] = sinf(ax); co[j + 16] = cosf(ax);
  }
}

// scene rope: (256,32), shared across batch
__global__ void rope_scene_k(float* __restrict__ ssin, float* __restrict__ scos)
{
  int t = blockIdx.x * blockDim.x + threadIdx.x;
  if (t >= 256) return;
  int iy = t / 16, ix = t % 16;
  float py = (iy + 0.5f) / 16.f * 2.f - 1.f;
  float px = (ix + 0.5f) / 16.f * 2.f - 1.f;
  float* so = ssin + (size_t)t * 32;
  float* co = scos + (size_t)t * 32;
  for (int j = 0; j < 16; j++) {
    float f  = powf(100.f, -(float)j / 16.f);
    float ay = py * f, ax = px * f;
    so[j]      = sinf(ay); co[j]      = cosf(ay);
    so[j + 16] = sinf(ax); co[j + 16] = cosf(ax);
  }
}

// ---------------------------------------------------------------------------
extern "C" void kernel_launch(void* const* d_in, const int* in_sizes, int n_in,
                              void* d_out, int out_size, void* d_ws, size_t ws_size,
                              hipStream_t stream)
{
  const float* in_local   = (const float*)d_in[0];
  const float* centers    = (const float*)d_in[1];
  const float* scales     = (const float*)d_in[2];
  const float* scene_tok  = (const float*)d_in[3];
  const float* read_gate  = (const float*)d_in[4];
  const float* write_gate = (const float*)d_in[5];
  const float* rWq = (const float*)d_in[6];
  const float* rWk = (const float*)d_in[7];
  const float* rWv = (const float*)d_in[8];
  const float* rWo = (const float*)d_in[9];
  const float* wWq = (const float*)d_in[10];
  const float* wWk = (const float*)d_in[11];
  const float* wWv = (const float*)d_in[12];
  const float* wWo = (const float*)d_in[13];
  const float* ln1_g = (const float*)d_in[14];
  const float* ln1_b = (const float*)d_in[15];
  const float* qkvW  = (const float*)d_in[16];
  const float* attnWo = (const float*)d_in[17];
  const float* ln2_g = (const float*)d_in[18];
  const float* ln2_b = (const float*)d_in[19];
  const float* mlpW1 = (const float*)d_in[20];
  const float* mlpW2 = (const float*)d_in[21];

  float* localp = (float*)d_out;                         // 6912 x 768
  float* scenep = localp + (size_t)ROWS_L * D_;          // 32768 x 768

  float* ws = (float*)d_ws;
  float* W1 = ws;                        // 25165824 (q buf / qkv)
  float* W2 = W1 + 25165824;             // 25165824 (k buf / mlp hidden)
  float* W3 = W2 + 25165824;             // 25165824 (v buf)
  float* W4 = W3 + 25165824;             // 25165824 (attn merged out)
  float* W5 = W4 + 25165824;             // 5308416  (LN out)
  float* LSIN = W5 + 5308416;            // 128*49*32 = 200704
  float* LCOS = LSIN + 200704;
  float* SSIN = LCOS + 200704;           // 8192
  float* SCOS = SSIN + 8192;

  // ---- init: local copy, scene broadcast, rope tables ----
  copy_f4<<<2048, 256, 0, stream>>>((const float4*)in_local, (float4*)localp,
                                    (int)((size_t)ROWS_L * D_ / 4));
  bcast_f4<<<2048, 256, 0, stream>>>((const float4*)scene_tok, (float4*)scenep,
                                     NS_ * D_ / 4, (int)((size_t)ROWS_S * D_ / 4));
  rope_local_k<<<(B_ * 49 + 255) / 256, 256, 0, stream>>>(centers, scales, LSIN, LCOS);
  rope_scene_k<<<1, 256, 0, stream>>>(SSIN, SCOS);

  auto gemm = [&](int epi, const float* A, const float* Bw, float* C,
                  const float* gate, int M, int N, int K) {
    dim3 g(N >> 6, M >> 6), blk(256);
    switch (epi) {
      case 0: gemm_f32<0><<<g, blk, 0, stream>>>(A, Bw, C, gate, M, N, K); break;
      case 1: gemm_f32<1><<<g, blk, 0, stream>>>(A, Bw, C, gate, M, N, K); break;
      case 2: gemm_f32<2><<<g, blk, 0, stream>>>(A, Bw, C, gate, M, N, K); break;
      default: gemm_f32<3><<<g, blk, 0, stream>>>(A, Bw, C, gate, M, N, K); break;
    }
  };

  const size_t WSZ = (size_t)D_ * D_;       // 589824
  const int LROPE_STR = 49 * 32;            // 1568

  for (int i = 0; i < L_; i++) {
    // ---------- read cross-attn: local += read_gate * CA(local, scene) ----
    gemm(0, localp, rWq + (size_t)i * WSZ, W1, nullptr, ROWS_L, D_, D_);
    gemm(0, scenep, rWk + (size_t)i * WSZ, W2, nullptr, ROWS_S, D_, D_);
    gemm(0, scenep, rWv + (size_t)i * WSZ, W3, nullptr, ROWS_S, D_, D_);
    attn_fused<<<dim3(1, NH_, B_), 64, 0, stream>>>(
        W1, D_, W2, D_, W3, D_, W4, D_, NL_, NS_,
        LSIN, LCOS, P_, LROPE_STR, SSIN, SCOS, 0, 0);
    gemm(2, W4, rWo + (size_t)i * WSZ, localp, read_gate + (size_t)i * D_,
         ROWS_L, D_, D_);

    // ---------- vit block ----------
    ln_kernel<<<ROWS_L / 4, 256, 0, stream>>>(localp, W5,
        ln1_g + (size_t)i * D_, ln1_b + (size_t)i * D_);
    gemm(0, W5, qkvW + (size_t)i * D_ * 3 * D_, W1, nullptr, ROWS_L, 3 * D_, D_);
    attn_fused<<<dim3(1, NH_, B_), 64, 0, stream>>>(
        W1, 3 * D_, W1 + D_, 3 * D_, W1 + 2 * D_, 3 * D_, W4, D_, NL_, NL_,
        LSIN, LCOS, P_, LROPE_STR, LSIN, LCOS, P_, LROPE_STR);
    gemm(1, W4, attnWo + (size_t)i * WSZ, localp, nullptr, ROWS_L, D_, D_);
    ln_kernel<<<ROWS_L / 4, 256, 0, stream>>>(localp, W5,
        ln2_g + (size_t)i * D_, ln2_b + (size_t)i * D_);
    gemm(3, W5, mlpW1 + (size_t)i * D_ * 4 * D_, W2, nullptr, ROWS_L, 4 * D_, D_);
    gemm(1, W2, mlpW2 + (size_t)i * 4 * D_ * D_, localp, nullptr, ROWS_L, D_, 4 * D_);

    // ---------- write cross-attn: scene += write_gate * CA(scene, local) --
    gemm(0, scenep, wWq + (size_t)i * WSZ, W1, nullptr, ROWS_S, D_, D_);
    gemm(0, localp, wWk + (size_t)i * WSZ, W2, nullptr, ROWS_L, D_, D_);
    gemm(0, localp, wWv + (size_t)i * WSZ, W3, nullptr, ROWS_L, D_, D_);
    attn_fused<<<dim3(4, NH_, B_), 64, 0, stream>>>(
        W1, D_, W2, D_, W3, D_, W4, D_, NS_, NL_,
        SSIN, SCOS, 0, 0, LSIN, LCOS, P_, LROPE_STR);
    gemm(2, W4, wWo + (size_t)i * WSZ, scenep, write_gate + (size_t)i * D_,
         ROWS_S, D_, D_);
  }
}